// Round 11
// baseline (302.125 us; speedup 1.0000x reference)
//
#include <hip/hip_runtime.h>
#include <hip/hip_bf16.h>

#define D 64
#define BSHIFT 8           // 256 nodes per bucket
#define BNODES 256
#define BCAP 4096          // edge capacity per bucket region (exp 2558, +30 sigma)
#define PTILE 2048         // edges per partition tile

typedef __attribute__((ext_vector_type(8))) short short8;
typedef __attribute__((ext_vector_type(4))) float float4v;

// flags[0] = 1 if float tensors are fp32 (else bf16)
// flags[1] = 1 if edge_index is int64 (else int32)

__device__ __forceinline__ float bf16u_to_f32(unsigned short u) {
  union { unsigned int i; float f; } c;
  c.i = ((unsigned int)u) << 16;
  return c.f;
}

__device__ __forceinline__ unsigned short f32_to_bf16u(float f) {
  union { float f; unsigned int u; } c;
  c.f = f;
  unsigned int r = (c.u + 0x7fffu + ((c.u >> 16) & 1u)) >> 16;  // RNE
  return (unsigned short)r;
}

// ---------------- probe dtypes ----------------

__global__ void k_probe(const void* W, const void* ei, int* flags) {
  int lane = threadIdx.x & 63;
  const unsigned short* wb = (const unsigned short*)W;
  bool big = false;
  for (int i = lane; i < 512; i += 64) {
    float v = bf16u_to_f32(wb[i]);
    if (!(fabsf(v) < 100.f)) big = true;  // NaN lands here too
  }
  int anybig = __any(big);
  const int* e32 = (const int*)ei;
  bool nz = (e32[2 * lane + 1] != 0);  // odd words of first 64 pairs
  int anynz = __any(nz);
  if (threadIdx.x == 0) {
    flags[0] = anybig ? 1 : 0;  // huge magnitudes => data is actually fp32
    flags[1] = anynz ? 0 : 1;   // all-zero odd words => int64
  }
}

// ---------------- weight prep + cursor init (parallel) ----------------

__global__ __launch_bounds__(256) void k_prep(
    const void* __restrict__ Ws, const void* __restrict__ Wout,
    const void* __restrict__ bs, const void* __restrict__ bout,
    const int* __restrict__ flags, unsigned short* __restrict__ WT,
    float* __restrict__ biasf, int* __restrict__ bucket_cursor) {
  int f32 = flags[0];
  int gid = blockIdx.x * 256 + threadIdx.x;
  int stride = gridDim.x * 256;

  for (int i = gid; i < 512; i += stride) bucket_cursor[i] = i * BCAP;

  // transpose 4 weight matrices into WT[l][n][k] (bf16)
  for (int i = gid; i < 4 * 4096; i += stride) {
    int l = i >> 12;
    int r = i & 4095;
    int k = r >> 6;
    int nn = r & 63;
    unsigned short v;
    if (l < 3) {
      v = f32 ? f32_to_bf16u(((const float*)Ws)[l * 4096 + r])
              : ((const unsigned short*)Ws)[l * 4096 + r];
    } else {
      v = f32 ? f32_to_bf16u(((const float*)Wout)[r])
              : ((const unsigned short*)Wout)[r];
    }
    WT[l * 4096 + nn * 64 + k] = v;
  }
  // biases -> fp32
  for (int i = gid; i < 4 * 64; i += stride) {
    int l = i >> 6;
    int j = i & 63;
    float v;
    if (l < 3)
      v = f32 ? ((const float*)bs)[l * 64 + j]
              : bf16u_to_f32(((const unsigned short*)bs)[l * 64 + j]);
    else
      v = f32 ? ((const float*)bout)[j]
              : bf16u_to_f32(((const unsigned short*)bout)[j]);
    biasf[i] = v;
  }
}

// ---------------- bucketed partition (fixed-capacity regions) ----------------

__global__ __launch_bounds__(256) void k_partition(
    const void* __restrict__ ei, const int* __restrict__ flags,
    int* __restrict__ bucket_cursor, int* __restrict__ packed, int e) {
  __shared__ int lhist[512];
  __shared__ int lbase[512];
  int tid = threadIdx.x;
  int t0 = blockIdx.x * PTILE;
  int tend = min(t0 + PTILE, e);
  if (t0 >= e) return;
  int i64 = flags[1];

  for (int b = tid; b < 512; b += 256) lhist[b] = 0;
  __syncthreads();

  if (i64) {
    const long long* dst = (const long long*)ei + e;
    for (int i = t0 + tid; i < tend; i += 256)
      atomicAdd(&lhist[((int)dst[i]) >> BSHIFT], 1);
  } else {
    const int* dst = (const int*)ei + e;
    for (int i = t0 + tid; i < tend; i += 256)
      atomicAdd(&lhist[dst[i] >> BSHIFT], 1);
  }
  __syncthreads();

  for (int b = tid; b < 512; b += 256) {
    int c = lhist[b];
    lbase[b] = c ? atomicAdd(&bucket_cursor[b], c) : 0;
    lhist[b] = 0;  // reuse as rank counter
  }
  __syncthreads();

  if (i64) {
    const long long* srcp = (const long long*)ei;
    const long long* dstp = srcp + e;
    for (int i = t0 + tid; i < tend; i += 256) {
      int s = (int)srcp[i];
      int d = (int)dstp[i];
      int b = d >> BSHIFT;
      int r = atomicAdd(&lhist[b], 1);
      packed[lbase[b] + r] = (s << BSHIFT) | (d & (BNODES - 1));
    }
  } else {
    const int* srcp = (const int*)ei;
    const int* dstp = srcp + e;
    for (int i = t0 + tid; i < tend; i += 256) {
      int s = srcp[i];
      int d = dstp[i];
      int b = d >> BSHIFT;
      int r = atomicAdd(&lhist[b], 1);
      packed[lbase[b] + r] = (s << BSHIFT) | (d & (BNODES - 1));
    }
  }
}

// One block per bucket: LDS counting sort -> per-node src list (grouped by
// dst) in the bucket's csr region, rowrange (beg,end), dinv.
__global__ __launch_bounds__(256) void k_sort_csr(
    const int* __restrict__ packed, const int* __restrict__ bucket_cursor,
    int* __restrict__ csr, int2* __restrict__ rowrange,
    float* __restrict__ dinv, int n) {
  __shared__ int lcnt[BNODES];
  __shared__ int lofs[BNODES];
  __shared__ int sbuf[BNODES];
  int tid = threadIdx.x;
  int bucket = blockIdx.x;
  int node0 = bucket << BSHIFT;
  int nodes = min(BNODES, n - node0);
  int s0 = bucket * BCAP;
  int s1 = bucket_cursor[bucket];  // region end after partition
  lcnt[tid] = 0;
  __syncthreads();
  for (int i = s0 + tid; i < s1; i += 256)
    atomicAdd(&lcnt[packed[i] & (BNODES - 1)], 1);
  __syncthreads();
  int v = lcnt[tid];
  sbuf[tid] = v;
  __syncthreads();
  for (int off = 1; off < BNODES; off <<= 1) {
    int tv = (tid >= off) ? sbuf[tid - off] : 0;
    __syncthreads();
    sbuf[tid] += tv;
    __syncthreads();
  }
  int excl = sbuf[tid] - v;
  lofs[tid] = excl;
  lcnt[tid] = 0;  // reuse as rank counter
  if (tid < nodes) {
    rowrange[node0 + tid] = make_int2(s0 + excl, s0 + excl + v);
    dinv[node0 + tid] = rsqrtf((float)(v + 1));  // +1 = self loop
  }
  __syncthreads();
  for (int i = s0 + tid; i < s1; i += 256) {
    int pk = packed[i];
    int ld = pk & (BNODES - 1);
    int r = atomicAdd(&lcnt[ld], 1);
    csr[s0 + lofs[ld] + r] = pk >> BSHIFT;
  }
}

// ---------------- z0 = dinv * x0, written SLICE-MAJOR ----------------
// zs[slice][node][16 feats] (32 B per node per slice), slice region = nr*32 B.
// Block: 256 nodes. Stage rows in LDS (stride 76 ushorts to spread banks),
// then write each slice's 32 B chunks coalesced.

__global__ __launch_bounds__(256) void k_scale_sliced(
    const void* __restrict__ x0, const int* __restrict__ flags,
    const float* __restrict__ dinv, unsigned short* __restrict__ zs, int n,
    int nr) {
  __shared__ unsigned short xt[256 * 76];
  int tid = threadIdx.x;
  int node0 = blockIdx.x * 256;
  int f32 = flags[0];

  if (f32) {
    const float* xf = (const float*)x0;
    for (int idx = tid; idx < 256 * 16; idx += 256) {
      int nl = idx >> 4;
      int c = idx & 15;
      if (node0 + nl < n) {
        float4 v = *(const float4*)(xf + (size_t)(node0 + nl) * 64 + c * 4);
        ushort4 o;
        o.x = f32_to_bf16u(v.x);
        o.y = f32_to_bf16u(v.y);
        o.z = f32_to_bf16u(v.z);
        o.w = f32_to_bf16u(v.w);
        *(ushort4*)&xt[nl * 76 + c * 4] = o;
      }
    }
  } else {
    const unsigned short* xb = (const unsigned short*)x0;
    for (int idx = tid; idx < 256 * 8; idx += 256) {
      int nl = idx >> 3;
      int c = idx & 7;
      if (node0 + nl < n) {
        short8 v = *(const short8*)(xb + (size_t)(node0 + nl) * 64 + c * 8);
        *(short8*)&xt[nl * 76 + c * 8] = v;
      }
    }
  }
  __syncthreads();

  // write sliced: 4 slices x 256 nodes x 2 chunks of 8 ushorts
  for (int u = tid; u < 2048; u += 256) {
    int slice = u >> 9;
    int rem = u & 511;
    int nl = rem >> 1;
    int h = rem & 1;
    int node = node0 + nl;
    if (node < n) {
      float dv = dinv[node];
      const unsigned short* src = &xt[nl * 76 + slice * 16 + h * 8];
      unsigned short o[8];
#pragma unroll
      for (int k = 0; k < 8; k++) o[k] = f32_to_bf16u(dv * bf16u_to_f32(src[k]));
      short8 ov;
#pragma unroll
      for (int k = 0; k < 8; k++) ov[k] = (short)o[k];
      *(short8*)(zs + (size_t)slice * nr * 16 + (size_t)node * 16 + h * 8) = ov;
    }
  }
}

// ---------------- sliced aggregation ----------------
// y[slice][node] = dinv_node * (z[slice][node] + sum_src z[slice][src]).
// slot = blockIdx%8: slice = slot&3, half = slot>>2. With round-robin
// block->XCD dispatch, all blocks touching slice region s run on XCDs {s,s+4}
// -> 3.2 MB working set fits the 4 MiB per-XCD L2 (vs 12.8 MB thrash before).
// One lane per node: 64 independent 2x16B gathers per instruction, 2-edge
// unroll. csr ranges of consecutive nodes are adjacent (bucketed sort).
__global__ __launch_bounds__(256) void k_agg_sliced(
    const unsigned short* __restrict__ zs, const int2* __restrict__ rowrange,
    const int* __restrict__ csr, const float* __restrict__ dinv,
    unsigned short* __restrict__ ys, int n, int nr) {
  int slot = blockIdx.x & 7;
  int chunk = blockIdx.x >> 3;
  int slice = slot & 3;
  int half = slot >> 2;
  int node = chunk * 512 + half * 256 + threadIdx.x;
  if (node >= n) return;

  const unsigned short* zb = zs + (size_t)slice * nr * 16;
  int2 rr = rowrange[node];
  float dv = dinv[node];

  float acc[16];
  {
    short8 s0 = *(const short8*)(zb + (size_t)node * 16);
    short8 s1 = *(const short8*)(zb + (size_t)node * 16 + 8);
#pragma unroll
    for (int k = 0; k < 8; k++) {
      acc[k] = bf16u_to_f32((unsigned short)s0[k]);
      acc[8 + k] = bf16u_to_f32((unsigned short)s1[k]);
    }
  }

  int i = rr.x;
  for (; i + 1 < rr.y; i += 2) {
    int sa = csr[i];
    int sb = csr[i + 1];
    short8 a0 = *(const short8*)(zb + (size_t)sa * 16);
    short8 a1 = *(const short8*)(zb + (size_t)sa * 16 + 8);
    short8 b0 = *(const short8*)(zb + (size_t)sb * 16);
    short8 b1 = *(const short8*)(zb + (size_t)sb * 16 + 8);
#pragma unroll
    for (int k = 0; k < 8; k++) {
      acc[k] += bf16u_to_f32((unsigned short)a0[k]);
      acc[8 + k] += bf16u_to_f32((unsigned short)a1[k]);
      acc[k] += bf16u_to_f32((unsigned short)b0[k]);
      acc[8 + k] += bf16u_to_f32((unsigned short)b1[k]);
    }
  }
  if (i < rr.y) {
    int sa = csr[i];
    short8 a0 = *(const short8*)(zb + (size_t)sa * 16);
    short8 a1 = *(const short8*)(zb + (size_t)sa * 16 + 8);
#pragma unroll
    for (int k = 0; k < 8; k++) {
      acc[k] += bf16u_to_f32((unsigned short)a0[k]);
      acc[8 + k] += bf16u_to_f32((unsigned short)a1[k]);
    }
  }

  short8 o0, o1;
#pragma unroll
  for (int k = 0; k < 8; k++) {
    o0[k] = (short)f32_to_bf16u(dv * acc[k]);
    o1[k] = (short)f32_to_bf16u(dv * acc[8 + k]);
  }
  unsigned short* yb = ys + (size_t)slice * nr * 16 + (size_t)node * 16;
  *(short8*)(yb) = o0;
  *(short8*)(yb + 8) = o1;
}

// ---------------- mid-layer GEMM (reads sliced y) ----------------
// scale_out=1: out (sliced z') = dinv * relu(yW+b)
// scale_out=0: out (row-major x') = relu(yW+b)
// A-frag k-range q*8..q*8+7 maps to slice q>>1, offset (q&1)*8; a1 = +2 slices.
__global__ __launch_bounds__(256) void k_gemm_mid(
    const unsigned short* __restrict__ ys,
    const unsigned short* __restrict__ WT, const float* __restrict__ bias,
    const float* __restrict__ dinv, unsigned short* __restrict__ out,
    int ntiles, int nr, int scale_out) {
  int lane = threadIdx.x & 63;
  int wid = threadIdx.x >> 6;
  int f = lane & 15;
  int q = lane >> 4;

  short8 bfr[4][2];
#pragma unroll
  for (int ct = 0; ct < 4; ct++)
#pragma unroll
    for (int kt = 0; kt < 2; kt++)
      bfr[ct][kt] =
          *(const short8*)(WT + (size_t)(f + 16 * ct) * 64 + kt * 32 + q * 8);

  float bv[4];
#pragma unroll
  for (int ct = 0; ct < 4; ct++) bv[ct] = bias[f + 16 * ct];

  size_t slice_stride = (size_t)nr * 16;
  int wave = blockIdx.x * 4 + wid;
  int nwaves = gridDim.x * 4;
  for (int t = wave; t < ntiles; t += nwaves) {
    int row0 = t * 16;
    const unsigned short* ar =
        ys + (size_t)(q >> 1) * slice_stride + (size_t)(row0 + f) * 16 +
        (q & 1) * 8;
    short8 a0 = *(const short8*)(ar);
    short8 a1 = *(const short8*)(ar + 2 * slice_stride);
    float4v acc[4];
#pragma unroll
    for (int ct = 0; ct < 4; ct++) {
      float4v z = {0.f, 0.f, 0.f, 0.f};
      acc[ct] =
          __builtin_amdgcn_mfma_f32_16x16x32_bf16(a0, bfr[ct][0], z, 0, 0, 0);
      acc[ct] = __builtin_amdgcn_mfma_f32_16x16x32_bf16(a1, bfr[ct][1],
                                                        acc[ct], 0, 0, 0);
    }
    if (scale_out) {
      float4 dv4 = *(const float4*)(dinv + row0 + q * 4);
      float d[4] = {dv4.x, dv4.y, dv4.z, dv4.w};
#pragma unroll
      for (int reg = 0; reg < 4; reg++) {
        int row = row0 + q * 4 + reg;
#pragma unroll
        for (int ct = 0; ct < 4; ct++)
          out[(size_t)ct * slice_stride + (size_t)row * 16 + f] =
              f32_to_bf16u(d[reg] * fmaxf(acc[ct][reg] + bv[ct], 0.f));
      }
    } else {
#pragma unroll
      for (int reg = 0; reg < 4; reg++) {
        int row = row0 + q * 4 + reg;
#pragma unroll
        for (int ct = 0; ct < 4; ct++)
          out[(size_t)row * 64 + 16 * ct + f] =
              f32_to_bf16u(fmaxf(acc[ct][reg] + bv[ct], 0.f));
      }
    }
  }
}

// ---------------- final projection GEMM (row-major x in) ----------------
__global__ __launch_bounds__(256) void k_gemm_final(
    const unsigned short* __restrict__ xin,
    const unsigned short* __restrict__ WT, const float* __restrict__ bias,
    void* __restrict__ out, const int* __restrict__ flags, int ntiles) {
  int lane = threadIdx.x & 63;
  int wid = threadIdx.x >> 6;
  int f = lane & 15;
  int q = lane >> 4;

  short8 bfr[4][2];
#pragma unroll
  for (int ct = 0; ct < 4; ct++)
#pragma unroll
    for (int kt = 0; kt < 2; kt++)
      bfr[ct][kt] =
          *(const short8*)(WT + (size_t)(f + 16 * ct) * 64 + kt * 32 + q * 8);

  int wave = blockIdx.x * 4 + wid;
  int nwaves = gridDim.x * 4;
  for (int t = wave; t < ntiles; t += nwaves) {
    int row0 = t * 16;
    const unsigned short* xr = xin + (size_t)(row0 + f) * 64 + q * 8;
    short8 a0 = *(const short8*)(xr);
    short8 a1 = *(const short8*)(xr + 32);
    float4v acc[4];
#pragma unroll
    for (int ct = 0; ct < 4; ct++) {
      float4v z = {0.f, 0.f, 0.f, 0.f};
      acc[ct] =
          __builtin_amdgcn_mfma_f32_16x16x32_bf16(a0, bfr[ct][0], z, 0, 0, 0);
      acc[ct] = __builtin_amdgcn_mfma_f32_16x16x32_bf16(a1, bfr[ct][1],
                                                        acc[ct], 0, 0, 0);
    }
    int f32o = flags[0];
    float bv[4];
#pragma unroll
    for (int ct = 0; ct < 4; ct++) bv[ct] = bias[f + 16 * ct];
    if (f32o) {
      float* op = (float*)out;
#pragma unroll
      for (int reg = 0; reg < 4; reg++) {
        size_t rb = (size_t)(row0 + q * 4 + reg) * 64 + f;
#pragma unroll
        for (int ct = 0; ct < 4; ct++) op[rb + 16 * ct] = acc[ct][reg] + bv[ct];
      }
    } else {
      unsigned short* op = (unsigned short*)out;
#pragma unroll
      for (int reg = 0; reg < 4; reg++) {
        size_t rb = (size_t)(row0 + q * 4 + reg) * 64 + f;
#pragma unroll
        for (int ct = 0; ct < 4; ct++)
          op[rb + 16 * ct] = f32_to_bf16u(acc[ct][reg] + bv[ct]);
      }
    }
  }
}

// ---------------- launch ----------------

extern "C" void kernel_launch(void* const* d_in, const int* in_sizes, int n_in,
                              void* d_out, int out_size, void* d_ws,
                              size_t ws_size, hipStream_t stream) {
  const void* x0 = d_in[0];
  const void* ei = d_in[1];
  const void* Ws = d_in[2];
  const void* bs = d_in[3];
  const void* Wout = d_in[4];
  const void* bout = d_in[5];

  const int N = in_sizes[0] / D;  // 100000
  const int E = in_sizes[1] / 2;  // 1000000
  const int NBUC = (N + BNODES - 1) >> BSHIFT;  // 391
  const int NT = (N + 15) / 16;  // 6250 row tiles
  const int NR = ((N + 511) / 512) * 512;  // 100352 (agg chunking)
  const int NCH = NR / 512;                // 196

  char* p = (char*)d_ws;
  auto alloc = [&](size_t bytes) {
    char* r = p;
    p += (bytes + 511) & ~(size_t)511;
    return r;
  };
  int* flags = (int*)alloc(8);
  int* bucket_cursor = (int*)alloc(512 * 4);
  int* packed = (int*)alloc((size_t)512 * BCAP * 4);
  int* csr = (int*)alloc((size_t)512 * BCAP * 4);
  int2* rowrange = (int2*)alloc((size_t)N * 8);
  float* dinv = (float*)alloc((size_t)N * 4);
  unsigned short* WT = (unsigned short*)alloc(4 * 4096 * 2);
  float* biasf = (float*)alloc(4 * 64 * 4);
  unsigned short* za = (unsigned short*)alloc((size_t)NR * D * 2);  // sliced
  unsigned short* zb = (unsigned short*)alloc((size_t)NR * D * 2);  // sliced
  unsigned short* yy = (unsigned short*)alloc((size_t)NR * D * 2);  // sliced
  unsigned short* x3 = (unsigned short*)alloc((size_t)N * D * 2);   // row-major
  (void)ws_size;
  (void)n_in;
  (void)out_size;

  k_probe<<<1, 64, 0, stream>>>(Ws, ei, flags);
  k_prep<<<32, 256, 0, stream>>>(Ws, Wout, bs, bout, flags, WT, biasf,
                                 bucket_cursor);
  int ptiles = (E + PTILE - 1) / PTILE;
  k_partition<<<ptiles, 256, 0, stream>>>(ei, flags, bucket_cursor, packed, E);
  k_sort_csr<<<NBUC, 256, 0, stream>>>(packed, bucket_cursor, csr, rowrange,
                                       dinv, N);
  k_scale_sliced<<<(N + 255) / 256, 256, 0, stream>>>(x0, flags, dinv, za, N,
                                                      NR);

  // L0: za -> yy -> zb (sliced)
  k_agg_sliced<<<8 * NCH, 256, 0, stream>>>(za, rowrange, csr, dinv, yy, N, NR);
  k_gemm_mid<<<(NT + 3) / 4, 256, 0, stream>>>(yy, WT + 0 * 4096,
                                               biasf + 0 * 64, dinv, zb, NT,
                                               NR, 1);
  // L1: zb -> yy -> za (sliced)
  k_agg_sliced<<<8 * NCH, 256, 0, stream>>>(zb, rowrange, csr, dinv, yy, N, NR);
  k_gemm_mid<<<(NT + 3) / 4, 256, 0, stream>>>(yy, WT + 1 * 4096,
                                               biasf + 1 * 64, dinv, za, NT,
                                               NR, 1);
  // L2: za -> yy -> x3 (row-major)
  k_agg_sliced<<<8 * NCH, 256, 0, stream>>>(za, rowrange, csr, dinv, yy, N, NR);
  k_gemm_mid<<<(NT + 3) / 4, 256, 0, stream>>>(yy, WT + 2 * 4096,
                                               biasf + 2 * 64, dinv, x3, NT,
                                               NR, 0);
  // final projection
  k_gemm_final<<<(NT + 3) / 4, 256, 0, stream>>>(x3, WT + 3 * 4096,
                                                 biasf + 3 * 64, d_out, flags,
                                                 NT);
}